// Round 1
// baseline (836.722 us; speedup 1.0000x reference)
//
#include <hip/hip_runtime.h>
#include <math.h>

// ---------------- workspace layout (float offsets) ----------------
#define WS_W2T   0          // 32*5*64      = 10240   w2t[(ci*5+k)*64+co]
#define WS_W3T   10240      // 64*3*128     = 24576   w3t[(ci*3+k)*128+co]
#define WS_A1    34816      // 32
#define WS_C1    34848      // 32
#define WS_A2    34880      // 64
#define WS_C2    34944      // 64
#define WS_A3    35008      // 128
#define WS_C3    35136      // 128  -> end 35264
#define WS_T1T   35264      // 131072   t1t[i*64+o]
#define WS_IS1T  166336     // 131072
#define WS_WW1T  297408     // 131072 -> end 428480
#define WS_T2T   428480     // 4096
#define WS_IS2T  432576
#define WS_WW2T  436672
#define WS_T3T   440768
#define WS_IS3T  444864
#define WS_WW3T  448960     // -> end 453056
#define WS_H2T   453056     // 1024*256*64 = 16777216   h2t[(b*256+l)*64+ci]
#define WS_FEAT  (453056 + 16777216)  // 1024*2048

struct InPtrs { const float* p[34]; };

__device__ __forceinline__ float gelu_exact(float v) {
    return 0.5f * v * (1.0f + erff(v * 0.70710678118654752f));
}

// ---------------- prep: pack/transpose params ----------------
__global__ __launch_bounds__(256) void prep_kernel(InPtrs in, float* __restrict__ ws) {
    int idx = blockIdx.x * 256 + threadIdx.x;
    if (idx >= 452832) return;
    if (idx < 10240) {                       // w2t
        int co = idx & 63; int r = idx >> 6; int k = r % 5; int ci = r / 5;
        ws[WS_W2T + idx] = in.p[7][co * 160 + ci * 5 + k];
    } else if (idx < 34816) {                // w3t
        int n = idx - 10240;
        int co = n & 127; int r = n >> 7; int k = r % 3; int ci = r / 3;
        ws[WS_W3T + n] = in.p[13][co * 192 + ci * 3 + k];
    } else if (idx < 35040) {                // BN folds: A = g*rsqrt(v+eps); C = (convb - m)*A + bnb
        int n = idx - 34816;
        int ch, offA, offC; const float *cb, *g, *bb, *m, *v;
        if (n < 32)      { ch = n;      cb = in.p[2];  g = in.p[3];  bb = in.p[4];  m = in.p[5];  v = in.p[6];  offA = WS_A1; offC = WS_C1; }
        else if (n < 96) { ch = n - 32; cb = in.p[8];  g = in.p[9];  bb = in.p[10]; m = in.p[11]; v = in.p[12]; offA = WS_A2; offC = WS_C2; }
        else             { ch = n - 96; cb = in.p[14]; g = in.p[15]; bb = in.p[16]; m = in.p[17]; v = in.p[18]; offA = WS_A3; offC = WS_C3; }
        float A = g[ch] * rsqrtf(v[ch] + 1e-5f);
        ws[offA + ch] = A;
        ws[offC + ch] = (cb[ch] - m[ch]) * A + bb[ch];
    } else if (idx < 428256) {               // wl1 transposes (t, 1/(s+1e-8), w)
        int n = idx - 35040;
        int arr = n / 131072; int m = n - arr * 131072;
        int o = m >> 11; int i = m & 2047;
        float val = in.p[19 + arr][o * 2048 + i];
        if (arr == 1) val = 1.0f / (val + 1e-8f);
        int base = (arr == 0) ? WS_T1T : (arr == 1) ? WS_IS1T : WS_WW1T;
        ws[base + i * 64 + o] = val;
    } else {                                 // wl2/wl3 transposes
        int n = idx - 428256;
        int layer = n / 12288; int m = n - layer * 12288;
        int arr = m / 4096; int mm = m - arr * 4096;
        int o = mm >> 6; int i = mm & 63;
        float val = in.p[(layer == 0 ? 24 : 29) + arr][o * 64 + i];
        if (arr == 1) val = 1.0f / (val + 1e-8f);
        int base;
        if (layer == 0) base = (arr == 0) ? WS_T2T : (arr == 1) ? WS_IS2T : WS_WW2T;
        else            base = (arr == 0) ? WS_T3T : (arr == 1) ? WS_IS3T : WS_WW3T;
        ws[base + i * 64 + o] = val;
    }
}

// ---------------- K12: conv1+bn+gelu+pool fused into conv2+bn+gelu+pool ----------------
// grid: 1024 b * 4 l-quarters; block 256. Output h2t[(b*256+lp)*64+co].
__global__ __launch_bounds__(256) void k12_kernel(const float* __restrict__ x,
                                                  const float* __restrict__ w1,
                                                  const float* __restrict__ ws,
                                                  float* __restrict__ h2t) {
    __shared__ float xs[288];
    __shared__ float w1s[224];
    __shared__ float a1s[32], c1s[32];
    __shared__ __align__(16) float h1s[32 * 132];
    __shared__ __align__(16) float w2s[10240];
    __shared__ float a2s[64], c2s[64];

    int t = threadIdx.x;
    int b = blockIdx.x >> 2, q = blockIdx.x & 3;
    int xbase = 256 * q - 8;

    for (int jj = t; jj < 280; jj += 256) {
        int gx = xbase + jj;
        xs[jj] = (gx >= 0 && gx < 1024) ? x[b * 1024 + gx] : 0.0f;
    }
    if (t < 224) w1s[t] = w1[t];
    if (t < 32) { a1s[t] = ws[WS_A1 + t]; c1s[t] = ws[WS_C1 + t]; }
    if (t < 64) { a2s[t] = ws[WS_A2 + t]; c2s[t] = ws[WS_C2 + t]; }
    {
        const float4* src = (const float4*)(ws + WS_W2T);
        float4* dst = (float4*)w2s;
        for (int i = t; i < 2560; i += 256) dst[i] = src[i];
    }
    __syncthreads();

    // stage B: h1 pooled tile, j in [0,132) -> lp = 128q-2+j
    for (int item = t; item < 32 * 132; item += 256) {
        int ci = item / 132;
        int j = item - ci * 132;
        int lp = 128 * q - 2 + j;
        float outv = 0.0f;
        if (lp >= 0 && lp < 512) {
            float d0 = 0.0f, d1 = 0.0f;
            #pragma unroll
            for (int k = 0; k < 7; ++k) {
                float w = w1s[ci * 7 + k];
                d0 += w * xs[2 * j + k + 1];
                d1 += w * xs[2 * j + k + 2];
            }
            float A = a1s[ci], C = c1s[ci];
            float g0 = gelu_exact(d0 * A + C);
            float g1 = gelu_exact(d1 * A + C);
            outv = fmaxf(g0, g1);
        }
        h1s[item] = outv;
    }
    __syncthreads();

    // stage C: conv2. lane = co, wave handles 4 groups of 8 conv positions.
    int wv = t >> 6, lane = t & 63;
    float A2 = a2s[lane], C2 = c2s[lane];
    for (int g4 = 0; g4 < 4; ++g4) {
        int g = wv * 4 + g4;
        float acc[8];
        #pragma unroll
        for (int p = 0; p < 8; ++p) acc[p] = 0.0f;
        for (int ci = 0; ci < 32; ++ci) {
            const float4* xp = (const float4*)(h1s + ci * 132 + 8 * g);
            float4 X0 = xp[0], X1 = xp[1], X2 = xp[2];
            float xv[12] = {X0.x, X0.y, X0.z, X0.w, X1.x, X1.y, X1.z, X1.w,
                            X2.x, X2.y, X2.z, X2.w};
            int wb = ci * 5 * 64 + lane;
            float wk0 = w2s[wb], wk1 = w2s[wb + 64], wk2 = w2s[wb + 128];
            float wk3 = w2s[wb + 192], wk4 = w2s[wb + 256];
            #pragma unroll
            for (int p = 0; p < 8; ++p)
                acc[p] += xv[p] * wk0 + xv[p + 1] * wk1 + xv[p + 2] * wk2
                        + xv[p + 3] * wk3 + xv[p + 4] * wk4;
        }
        int lp0 = 64 * q + 4 * g;
        #pragma unroll
        for (int u = 0; u < 4; ++u) {
            float g0 = gelu_exact(acc[2 * u] * A2 + C2);
            float g1 = gelu_exact(acc[2 * u + 1] * A2 + C2);
            h2t[(b * 256 + lp0 + u) * 64 + lane] = fmaxf(g0, g1);
        }
    }
}

// ---------------- K3: conv3+bn+gelu+avgpool16 -> feat (B,2048) ----------------
// grid: 1024 b * 8 l-chunks of 32; block 256.
__global__ __launch_bounds__(256) void k3_kernel(const float* __restrict__ ws,
                                                 float* __restrict__ feat) {
    __shared__ __align__(16) float w3s[12288];
    __shared__ __align__(16) float xs3[32 * 36];
    __shared__ float part[4][128];

    int t = threadIdx.x;
    int b = blockIdx.x >> 3, lc = blockIdx.x & 7;
    int l0 = lc * 32;
    int wv = t >> 6, lane = t & 63;
    const float* h2t = ws + WS_H2T;

    float acc0[8], acc1[8];
    #pragma unroll
    for (int p = 0; p < 8; ++p) { acc0[p] = 0.0f; acc1[p] = 0.0f; }

    for (int ch = 0; ch < 2; ++ch) {
        __syncthreads();
        for (int item = t; item < 32 * 34; item += 256) {
            int jj = item >> 5, ci = item & 31;
            int l = l0 + jj - 1;
            xs3[ci * 36 + jj] = (l >= 0 && l < 256)
                ? h2t[(b * 256 + l) * 64 + 32 * ch + ci] : 0.0f;
        }
        {
            const float4* src = (const float4*)(ws + WS_W3T + 12288 * ch);
            float4* dst = (float4*)w3s;
            for (int i = t; i < 3072; i += 256) dst[i] = src[i];
        }
        __syncthreads();
        for (int ci = 0; ci < 32; ++ci) {
            const float4* xp = (const float4*)(xs3 + ci * 36 + 8 * wv);
            float4 X0 = xp[0], X1 = xp[1], X2 = xp[2];
            float xv[12] = {X0.x, X0.y, X0.z, X0.w, X1.x, X1.y, X1.z, X1.w,
                            X2.x, X2.y, X2.z, X2.w};
            int wb = ci * 3 * 128 + lane;
            float wl0 = w3s[wb],        wl1 = w3s[wb + 128], wl2 = w3s[wb + 256];
            float wh0 = w3s[wb + 64],   wh1 = w3s[wb + 192], wh2 = w3s[wb + 320];
            #pragma unroll
            for (int p = 0; p < 8; ++p) {
                acc0[p] += xv[p] * wl0 + xv[p + 1] * wl1 + xv[p + 2] * wl2;
                acc1[p] += xv[p] * wh0 + xv[p + 1] * wh1 + xv[p + 2] * wh2;
            }
        }
    }
    float A0 = ws[WS_A3 + lane],      C0 = ws[WS_C3 + lane];
    float A1 = ws[WS_A3 + 64 + lane], C1 = ws[WS_C3 + 64 + lane];
    float s0 = 0.0f, s1 = 0.0f;
    #pragma unroll
    for (int p = 0; p < 8; ++p) {
        s0 += gelu_exact(acc0[p] * A0 + C0);
        s1 += gelu_exact(acc1[p] * A1 + C1);
    }
    part[wv][lane] = s0;
    part[wv][lane + 64] = s1;
    __syncthreads();
    int bh = t >> 7, co = t & 127;
    float sum = part[2 * bh][co] + part[2 * bh + 1][co];
    int bin = (l0 >> 4) + bh;
    feat[b * 2048 + co * 16 + bin] = sum * 0.0625f;
}

// ---------------- K4: wavelet-KAN head, fully fused ----------------
// grid: 256 blocks (4 batch rows each); block 256 = 4 waves; wave w owns batch row b0+w.
__device__ __forceinline__ float wave_sum(float v) {
    #pragma unroll
    for (int off = 32; off > 0; off >>= 1) v += __shfl_xor(v, off, 64);
    return v;
}
__device__ __forceinline__ float silu_f(float v) {
    return v / (1.0f + __expf(-v));
}

__global__ __launch_bounds__(256) void k4_kernel(const float* __restrict__ ws,
        const float* __restrict__ ln1g, const float* __restrict__ ln1b,
        const float* __restrict__ ln2g, const float* __restrict__ ln2b,
        const float* __restrict__ ln3g, const float* __restrict__ ln3b,
        float* __restrict__ out) {
    __shared__ __align__(16) float fs[4 * 2048];
    __shared__ float red[4 * 64 * 4];

    int t = threadIdx.x;
    int b0 = blockIdx.x * 4;
    const float* feat = ws + WS_FEAT;
    {
        const float4* src = (const float4*)(feat + b0 * 2048);
        float4* dst = (float4*)fs;
        for (int i = t; i < 2048; i += 256) dst[i] = src[i];
    }
    __syncthreads();

    int o = t & 63, grp = t >> 6;
    const float* t1t  = ws + WS_T1T;
    const float* is1t = ws + WS_IS1T;
    const float* w1t  = ws + WS_WW1T;
    float acc0 = 0.0f, acc1 = 0.0f, acc2 = 0.0f, acc3 = 0.0f;
    int i0 = grp * 512;
    for (int i = i0; i < i0 + 512; ++i) {
        float tv = t1t[i * 64 + o], sv = is1t[i * 64 + o], wv = w1t[i * 64 + o];
        float z, z2;
        z = (fs[i] - tv) * sv;        z2 = z * z; acc0 += (1.0f - z2) * __expf(-0.5f * z2) * wv;
        z = (fs[2048 + i] - tv) * sv; z2 = z * z; acc1 += (1.0f - z2) * __expf(-0.5f * z2) * wv;
        z = (fs[4096 + i] - tv) * sv; z2 = z * z; acc2 += (1.0f - z2) * __expf(-0.5f * z2) * wv;
        z = (fs[6144 + i] - tv) * sv; z2 = z * z; acc3 += (1.0f - z2) * __expf(-0.5f * z2) * wv;
    }
    red[(0 * 64 + o) * 4 + grp] = acc0;
    red[(1 * 64 + o) * 4 + grp] = acc1;
    red[(2 * 64 + o) * 4 + grp] = acc2;
    red[(3 * 64 + o) * 4 + grp] = acc3;
    __syncthreads();

    int w = t >> 6;  // wave -> batch row b0+w, lane -> o
    float y = red[(w * 64 + o) * 4 + 0] + red[(w * 64 + o) * 4 + 1]
            + red[(w * 64 + o) * 4 + 2] + red[(w * 64 + o) * 4 + 3];

    // silu + LN1
    y = silu_f(y);
    float m = wave_sum(y) * 0.015625f;
    float d = y - m;
    float var = wave_sum(d * d) * 0.015625f;
    float yn = d * rsqrtf(var + 1e-5f) * ln1g[o] + ln1b[o];

    // wl2
    {
        const float* t2t  = ws + WS_T2T;
        const float* is2t = ws + WS_IS2T;
        const float* w2t  = ws + WS_WW2T;
        float a = 0.0f;
        for (int i = 0; i < 64; ++i) {
            float xi = __shfl(yn, i, 64);
            float tv = t2t[i * 64 + o], sv = is2t[i * 64 + o], wv = w2t[i * 64 + o];
            float z = (xi - tv) * sv, z2 = z * z;
            a += (1.0f - z2) * __expf(-0.5f * z2) * wv;
        }
        float y2 = silu_f(a);
        float m2 = wave_sum(y2) * 0.015625f;
        float d2 = y2 - m2;
        float v2 = wave_sum(d2 * d2) * 0.015625f;
        yn = d2 * rsqrtf(v2 + 1e-5f) * ln2g[o] + ln2b[o];
    }
    // wl3
    {
        const float* t3t  = ws + WS_T3T;
        const float* is3t = ws + WS_IS3T;
        const float* w3t  = ws + WS_WW3T;
        float a = 0.0f;
        for (int i = 0; i < 64; ++i) {
            float xi = __shfl(yn, i, 64);
            float tv = t3t[i * 64 + o], sv = is3t[i * 64 + o], wv = w3t[i * 64 + o];
            float z = (xi - tv) * sv, z2 = z * z;
            a += (1.0f - z2) * __expf(-0.5f * z2) * wv;
        }
        float y3 = silu_f(a);
        float m3 = wave_sum(y3) * 0.015625f;
        float d3 = y3 - m3;
        float v3 = wave_sum(d3 * d3) * 0.015625f;
        yn = d3 * rsqrtf(v3 + 1e-5f) * ln3g[o] + ln3b[o];
    }
    out[(b0 + w) * 64 + o] = yn;
}

// ---------------- launch ----------------
extern "C" void kernel_launch(void* const* d_in, const int* in_sizes, int n_in,
                              void* d_out, int out_size, void* d_ws, size_t ws_size,
                              hipStream_t stream) {
    float* ws = (float*)d_ws;
    InPtrs ip;
    for (int i = 0; i < 34; ++i) ip.p[i] = (const float*)d_in[i];

    prep_kernel<<<1769, 256, 0, stream>>>(ip, ws);
    k12_kernel<<<4096, 256, 0, stream>>>((const float*)d_in[0], (const float*)d_in[1],
                                         ws, ws + WS_H2T);
    k3_kernel<<<8192, 256, 0, stream>>>(ws, ws + WS_FEAT);
    k4_kernel<<<256, 256, 0, stream>>>(ws,
        (const float*)d_in[22], (const float*)d_in[23],
        (const float*)d_in[27], (const float*)d_in[28],
        (const float*)d_in[32], (const float*)d_in[33],
        (float*)d_out);
}

// Round 3
// 596.978 us; speedup vs baseline: 1.4016x; 1.4016x over previous
//
#include <hip/hip_runtime.h>
#include <hip/hip_bf16.h>
#include <math.h>

// ---------------- workspace layout (float offsets) ----------------
#define WS_W2T   0          // 32*5*64 = 10240 fp32   w2t[(ci*5+k)*64+co]
#define WS_W3H   10240      // 128*200 f16 = 12800 floats  w3h[co*200 + (tap*64+ci)]
#define WS_W3L   23040      // 128*200 f16 = 12800 floats  (residual lo)
#define WS_A1    35840      // 32
#define WS_C1    35872      // 32
#define WS_A2    35904      // 64
#define WS_C2    35968      // 64
#define WS_A3    36032      // 128
#define WS_C3    36160      // 128 -> 36288
#define WS_T1T   36288      // 131072   t1t[i*64+o]
#define WS_IS1T  167360     // 131072
#define WS_WW1T  298432     // 131072 -> 429504
#define WS_T2T   429504     // 4096
#define WS_IS2T  433600
#define WS_WW2T  437696
#define WS_T3T   441792
#define WS_IS3T  445888
#define WS_WW3T  449984     // -> 454080
#define WS_H2T   454080     // 1024*256*64 fp32 = 16777216
#define WS_FEAT  27231296_UNUSED
#define WS_FEAT2 (454080 + 16777216)   // 1024*2048 floats -> end 19328448

typedef _Float16 f16x8 __attribute__((ext_vector_type(8)));
typedef _Float16 f16x4 __attribute__((ext_vector_type(4)));
typedef float    f32x4 __attribute__((ext_vector_type(4)));

struct InPtrs { const float* p[34]; };

__device__ __forceinline__ float gelu_exact(float v) {
    return 0.5f * v * (1.0f + erff(v * 0.70710678118654752f));
}

// ---------------- prep: pack/transpose params ----------------
__global__ __launch_bounds__(256) void prep_kernel(InPtrs in, float* __restrict__ ws) {
    int idx = blockIdx.x * 256 + threadIdx.x;
    if (idx >= 453856) return;
    if (idx < 10240) {                       // w2t fp32
        int co = idx & 63; int r = idx >> 6; int k = r % 5; int ci = r / 5;
        ws[WS_W2T + idx] = in.p[7][co * 160 + ci * 5 + k];
    } else if (idx < 35840) {                // w3 split hi/lo fp16 [co][tap*64+ci], stride 200
        int n = idx - 10240;
        int co = n / 200; int k = n - co * 200;
        float val = 0.0f;
        if (k < 192) { int ci = k & 63; int tap = k >> 6; val = in.p[13][co * 192 + ci * 3 + tap]; }
        _Float16 hi = (_Float16)val;
        _Float16 lo = (_Float16)(val - (float)hi);
        ((_Float16*)(ws + WS_W3H))[co * 200 + k] = hi;
        ((_Float16*)(ws + WS_W3L))[co * 200 + k] = lo;
    } else if (idx < 36064) {                // BN folds
        int n = idx - 35840;
        int ch, offA, offC; const float *cb, *g, *bb, *m, *v;
        if (n < 32)      { ch = n;      cb = in.p[2];  g = in.p[3];  bb = in.p[4];  m = in.p[5];  v = in.p[6];  offA = WS_A1; offC = WS_C1; }
        else if (n < 96) { ch = n - 32; cb = in.p[8];  g = in.p[9];  bb = in.p[10]; m = in.p[11]; v = in.p[12]; offA = WS_A2; offC = WS_C2; }
        else             { ch = n - 96; cb = in.p[14]; g = in.p[15]; bb = in.p[16]; m = in.p[17]; v = in.p[18]; offA = WS_A3; offC = WS_C3; }
        float A = g[ch] * rsqrtf(v[ch] + 1e-5f);
        ws[offA + ch] = A;
        ws[offC + ch] = (cb[ch] - m[ch]) * A + bb[ch];
    } else if (idx < 429280) {               // wl1 transposes (t, 1/(s+1e-8), w)
        int n = idx - 36064;
        int arr = n / 131072; int m = n - arr * 131072;
        int o = m >> 11; int i = m & 2047;
        float val = in.p[19 + arr][o * 2048 + i];
        if (arr == 1) val = 1.0f / (val + 1e-8f);
        int base = (arr == 0) ? WS_T1T : (arr == 1) ? WS_IS1T : WS_WW1T;
        ws[base + i * 64 + o] = val;
    } else {                                 // wl2/wl3 transposes
        int n = idx - 429280;
        int layer = n / 12288; int m = n - layer * 12288;
        int arr = m / 4096; int mm = m - arr * 4096;
        int o = mm >> 6; int i = mm & 63;
        float val = in.p[(layer == 0 ? 24 : 29) + arr][o * 64 + i];
        if (arr == 1) val = 1.0f / (val + 1e-8f);
        int base;
        if (layer == 0) base = (arr == 0) ? WS_T2T : (arr == 1) ? WS_IS2T : WS_WW2T;
        else            base = (arr == 0) ? WS_T3T : (arr == 1) ? WS_IS3T : WS_WW3T;
        ws[base + i * 64 + o] = val;
    }
}

// ---------------- K12: conv1+bn+gelu+pool fused into conv2+bn+gelu+pool (fp32 VALU) ----------------
// grid: 1024 b * 4 l-quarters; block 256. Output h2t[(b*256+lp)*64+co] fp32 (verified round 1).
__global__ __launch_bounds__(256) void k12_kernel(const float* __restrict__ x,
                                                  const float* __restrict__ w1,
                                                  const float* __restrict__ ws,
                                                  float* __restrict__ h2t) {
    __shared__ float xs[288];
    __shared__ float w1s[224];
    __shared__ float a1s[32], c1s[32];
    __shared__ __align__(16) float h1s[32 * 132];
    __shared__ __align__(16) float w2s[10240];
    __shared__ float a2s[64], c2s[64];

    int t = threadIdx.x;
    int b = blockIdx.x >> 2, q = blockIdx.x & 3;
    int xbase = 256 * q - 8;

    for (int jj = t; jj < 280; jj += 256) {
        int gx = xbase + jj;
        xs[jj] = (gx >= 0 && gx < 1024) ? x[b * 1024 + gx] : 0.0f;
    }
    if (t < 224) w1s[t] = w1[t];
    if (t < 32) { a1s[t] = ws[WS_A1 + t]; c1s[t] = ws[WS_C1 + t]; }
    if (t < 64) { a2s[t] = ws[WS_A2 + t]; c2s[t] = ws[WS_C2 + t]; }
    {
        const float4* src = (const float4*)(ws + WS_W2T);
        float4* dst = (float4*)w2s;
        for (int i = t; i < 2560; i += 256) dst[i] = src[i];
    }
    __syncthreads();

    for (int item = t; item < 32 * 132; item += 256) {
        int ci = item / 132;
        int j = item - ci * 132;
        int lp = 128 * q - 2 + j;
        float outv = 0.0f;
        if (lp >= 0 && lp < 512) {
            float d0 = 0.0f, d1 = 0.0f;
            #pragma unroll
            for (int k = 0; k < 7; ++k) {
                float w = w1s[ci * 7 + k];
                d0 += w * xs[2 * j + k + 1];
                d1 += w * xs[2 * j + k + 2];
            }
            float A = a1s[ci], C = c1s[ci];
            float g0 = gelu_exact(d0 * A + C);
            float g1 = gelu_exact(d1 * A + C);
            outv = fmaxf(g0, g1);
        }
        h1s[item] = outv;
    }
    __syncthreads();

    int wv = t >> 6, lane = t & 63;
    float A2 = a2s[lane], C2 = c2s[lane];
    for (int g4 = 0; g4 < 4; ++g4) {
        int g = wv * 4 + g4;
        float acc[8];
        #pragma unroll
        for (int p = 0; p < 8; ++p) acc[p] = 0.0f;
        for (int ci = 0; ci < 32; ++ci) {
            const float4* xp = (const float4*)(h1s + ci * 132 + 8 * g);
            float4 X0 = xp[0], X1 = xp[1], X2 = xp[2];
            float xv[12] = {X0.x, X0.y, X0.z, X0.w, X1.x, X1.y, X1.z, X1.w,
                            X2.x, X2.y, X2.z, X2.w};
            int wb = ci * 5 * 64 + lane;
            float wk0 = w2s[wb], wk1 = w2s[wb + 64], wk2 = w2s[wb + 128];
            float wk3 = w2s[wb + 192], wk4 = w2s[wb + 256];
            #pragma unroll
            for (int p = 0; p < 8; ++p)
                acc[p] += xv[p] * wk0 + xv[p + 1] * wk1 + xv[p + 2] * wk2
                        + xv[p + 3] * wk3 + xv[p + 4] * wk4;
        }
        int lp0 = 64 * q + 4 * g;
        #pragma unroll
        for (int u = 0; u < 4; ++u) {
            float g0 = gelu_exact(acc[2 * u] * A2 + C2);
            float g1 = gelu_exact(acc[2 * u + 1] * A2 + C2);
            h2t[((size_t)b * 256 + lp0 + u) * 64 + lane] = fmaxf(g0, g1);
        }
    }
}

// ---------------- K3M: conv3 as split-fp16 MFMA GEMM + bn + gelu + avgpool16 ----------------
// out[l][co] = sum_k A[l][k]*Bt[co][k], k = tap*64+ci; A,B split hi/lo fp16 -> 3 MFMAs/tile.
// grid: 1024 b * 2 row-halves (128 l); block 256 = 4 waves (2x2); wave = 64 rows x 64 cols.
__global__ __launch_bounds__(256) void k3m_kernel(const float* __restrict__ h2t,
                                                  const _Float16* __restrict__ w3h,
                                                  const _Float16* __restrict__ w3l,
                                                  const float* __restrict__ ws,
                                                  float* __restrict__ feat) {
    __shared__ __align__(16) _Float16 Ah[130 * 72];  // stride 72: 2-way bank alias = free
    __shared__ __align__(16) _Float16 Al[130 * 72];

    int t = threadIdx.x;
    int b = blockIdx.x >> 1, q = blockIdx.x & 1;
    int l0 = q * 128;

    // stage A tile: 130 rows x 64 fp32 -> hi/lo fp16
    for (int item = t; item < 130 * 16; item += 256) {
        int r = item >> 4, seg = item & 15;
        int l = l0 - 1 + r;
        float4 v = make_float4(0.f, 0.f, 0.f, 0.f);
        if (l >= 0 && l < 256)
            v = *((const float4*)(h2t + ((size_t)b * 256 + l) * 64) + seg);
        _Float16 h0 = (_Float16)v.x, h1 = (_Float16)v.y,
                 h2 = (_Float16)v.z, h3 = (_Float16)v.w;
        f16x4 hv = {h0, h1, h2, h3};
        f16x4 lv = {(_Float16)(v.x - (float)h0), (_Float16)(v.y - (float)h1),
                    (_Float16)(v.z - (float)h2), (_Float16)(v.w - (float)h3)};
        int base = r * 72 + seg * 4;
        *(f16x4*)(&Ah[base]) = hv;
        *(f16x4*)(&Al[base]) = lv;
    }
    __syncthreads();

    int w = t >> 6, lane = t & 63;
    int wr = w >> 1, wc = w & 1;
    int m = lane & 15, quad = lane >> 4;

    f32x4 acc[4][4] = {};
    size_t boff = (size_t)(wc * 64 + m) * 200 + quad * 8;

    #pragma unroll
    for (int s = 0; s < 6; ++s) {
        int kbase = s * 32;
        int k = kbase + quad * 8;
        int koff = k >> 6, ci = k & 63;
        f16x8 ah[4], al[4], bh[4], bl[4];
        #pragma unroll
        for (int tr = 0; tr < 4; ++tr) {
            int row = 64 * wr + 16 * tr + m;
            ah[tr] = *(const f16x8*)(&Ah[(row + koff) * 72 + ci]);
            al[tr] = *(const f16x8*)(&Al[(row + koff) * 72 + ci]);
        }
        #pragma unroll
        for (int tc = 0; tc < 4; ++tc) {
            bh[tc] = *(const f16x8*)(w3h + boff + 16 * tc * 200 + kbase);
            bl[tc] = *(const f16x8*)(w3l + boff + 16 * tc * 200 + kbase);
        }
        #pragma unroll
        for (int tr = 0; tr < 4; ++tr)
            #pragma unroll
            for (int tc = 0; tc < 4; ++tc) {
                acc[tr][tc] = __builtin_amdgcn_mfma_f32_16x16x32_f16(ah[tr], bh[tc], acc[tr][tc], 0, 0, 0);
                acc[tr][tc] = __builtin_amdgcn_mfma_f32_16x16x32_f16(al[tr], bh[tc], acc[tr][tc], 0, 0, 0);
                acc[tr][tc] = __builtin_amdgcn_mfma_f32_16x16x32_f16(ah[tr], bl[tc], acc[tr][tc], 0, 0, 0);
            }
    }

    // epilogue: bn + gelu + 16-l avgpool. C/D: col=lane&15, row=quad*4+reg.
    #pragma unroll
    for (int tc = 0; tc < 4; ++tc) {
        int co = 64 * wc + 16 * tc + m;
        float A3 = ws[WS_A3 + co], C3 = ws[WS_C3 + co];
        #pragma unroll
        for (int tr = 0; tr < 4; ++tr) {
            float s = 0.0f;
            #pragma unroll
            for (int r = 0; r < 4; ++r)
                s += gelu_exact(acc[tr][tc][r] * A3 + C3);
            s += __shfl_xor(s, 16, 64);
            s += __shfl_xor(s, 32, 64);
            if (quad == 0) {
                int bin = (l0 >> 4) + 4 * wr + tr;
                feat[(size_t)b * 2048 + co * 16 + bin] = s * 0.0625f;
            }
        }
    }
}

// ---------------- K4: wavelet-KAN head, fully fused ----------------
__device__ __forceinline__ float wave_sum(float v) {
    #pragma unroll
    for (int off = 32; off > 0; off >>= 1) v += __shfl_xor(v, off, 64);
    return v;
}
__device__ __forceinline__ float silu_f(float v) {
    return v / (1.0f + __expf(-v));
}

__global__ __launch_bounds__(256) void k4_kernel(const float* __restrict__ ws,
        const float* __restrict__ ln1g, const float* __restrict__ ln1b,
        const float* __restrict__ ln2g, const float* __restrict__ ln2b,
        const float* __restrict__ ln3g, const float* __restrict__ ln3b,
        float* __restrict__ out) {
    __shared__ __align__(16) float fs[4 * 2048];
    __shared__ float red[4 * 64 * 4];

    int t = threadIdx.x;
    int b0 = blockIdx.x * 4;
    const float* feat = ws + WS_FEAT2;
    {
        const float4* src = (const float4*)(feat + (size_t)b0 * 2048);
        float4* dst = (float4*)fs;
        for (int i = t; i < 2048; i += 256) dst[i] = src[i];
    }
    __syncthreads();

    int o = t & 63, grp = t >> 6;
    const float* t1t  = ws + WS_T1T;
    const float* is1t = ws + WS_IS1T;
    const float* w1t  = ws + WS_WW1T;
    float acc0 = 0.0f, acc1 = 0.0f, acc2 = 0.0f, acc3 = 0.0f;
    int i0 = grp * 512;
    for (int i = i0; i < i0 + 512; ++i) {
        float tv = t1t[i * 64 + o], sv = is1t[i * 64 + o], wv = w1t[i * 64 + o];
        float z, z2;
        z = (fs[i] - tv) * sv;        z2 = z * z; acc0 += (1.0f - z2) * __expf(-0.5f * z2) * wv;
        z = (fs[2048 + i] - tv) * sv; z2 = z * z; acc1 += (1.0f - z2) * __expf(-0.5f * z2) * wv;
        z = (fs[4096 + i] - tv) * sv; z2 = z * z; acc2 += (1.0f - z2) * __expf(-0.5f * z2) * wv;
        z = (fs[6144 + i] - tv) * sv; z2 = z * z; acc3 += (1.0f - z2) * __expf(-0.5f * z2) * wv;
    }
    red[(0 * 64 + o) * 4 + grp] = acc0;
    red[(1 * 64 + o) * 4 + grp] = acc1;
    red[(2 * 64 + o) * 4 + grp] = acc2;
    red[(3 * 64 + o) * 4 + grp] = acc3;
    __syncthreads();

    int w = t >> 6;
    float y = red[(w * 64 + o) * 4 + 0] + red[(w * 64 + o) * 4 + 1]
            + red[(w * 64 + o) * 4 + 2] + red[(w * 64 + o) * 4 + 3];

    y = silu_f(y);
    float m = wave_sum(y) * 0.015625f;
    float d = y - m;
    float var = wave_sum(d * d) * 0.015625f;
    float yn = d * rsqrtf(var + 1e-5f) * ln1g[o] + ln1b[o];

    {
        const float* t2t  = ws + WS_T2T;
        const float* is2t = ws + WS_IS2T;
        const float* w2t  = ws + WS_WW2T;
        float a = 0.0f;
        for (int i = 0; i < 64; ++i) {
            float xi = __shfl(yn, i, 64);
            float tv = t2t[i * 64 + o], sv = is2t[i * 64 + o], wv = w2t[i * 64 + o];
            float z = (xi - tv) * sv, z2 = z * z;
            a += (1.0f - z2) * __expf(-0.5f * z2) * wv;
        }
        float y2 = silu_f(a);
        float m2 = wave_sum(y2) * 0.015625f;
        float d2 = y2 - m2;
        float v2 = wave_sum(d2 * d2) * 0.015625f;
        yn = d2 * rsqrtf(v2 + 1e-5f) * ln2g[o] + ln2b[o];
    }
    {
        const float* t3t  = ws + WS_T3T;
        const float* is3t = ws + WS_IS3T;
        const float* w3t  = ws + WS_WW3T;
        float a = 0.0f;
        for (int i = 0; i < 64; ++i) {
            float xi = __shfl(yn, i, 64);
            float tv = t3t[i * 64 + o], sv = is3t[i * 64 + o], wv = w3t[i * 64 + o];
            float z = (xi - tv) * sv, z2 = z * z;
            a += (1.0f - z2) * __expf(-0.5f * z2) * wv;
        }
        float y3 = silu_f(a);
        float m3 = wave_sum(y3) * 0.015625f;
        float d3 = y3 - m3;
        float v3 = wave_sum(d3 * d3) * 0.015625f;
        yn = d3 * rsqrtf(v3 + 1e-5f) * ln3g[o] + ln3b[o];
    }
    out[((size_t)b0 + w) * 64 + o] = yn;
}

// ---------------- launch ----------------
extern "C" void kernel_launch(void* const* d_in, const int* in_sizes, int n_in,
                              void* d_out, int out_size, void* d_ws, size_t ws_size,
                              hipStream_t stream) {
    float* ws = (float*)d_ws;
    InPtrs ip;
    for (int i = 0; i < 34; ++i) ip.p[i] = (const float*)d_in[i];

    prep_kernel<<<1774, 256, 0, stream>>>(ip, ws);
    k12_kernel<<<4096, 256, 0, stream>>>((const float*)d_in[0], (const float*)d_in[1],
                                         ws, ws + WS_H2T);
    k3m_kernel<<<2048, 256, 0, stream>>>(ws + WS_H2T,
                                         (const _Float16*)(ws + WS_W3H),
                                         (const _Float16*)(ws + WS_W3L),
                                         ws, ws + WS_FEAT2);
    k4_kernel<<<256, 256, 0, stream>>>(ws,
        (const float*)d_in[22], (const float*)d_in[23],
        (const float*)d_in[27], (const float*)d_in[28],
        (const float*)d_in[32], (const float*)d_in[33],
        (float*)d_out);
}

// Round 4
// 407.895 us; speedup vs baseline: 2.0513x; 1.4636x over previous
//
#include <hip/hip_runtime.h>
#include <hip/hip_bf16.h>
#include <math.h>

// ---------------- workspace layout (float offsets) ----------------
#define WS_W2H   0          // 64*160 f16 = 5120 floats   w2h[co*160 + (tap*32+ci)]
#define WS_W2L   5120       // residual plane
#define WS_W3H   10240      // 128*200 f16 = 12800 floats w3h[co*200 + (tap*64+ci)]
#define WS_W3L   23040      // -> 35840
#define WS_A1    35840      // 32
#define WS_C1    35872      // 32
#define WS_A2    35904      // 64
#define WS_C2    35968      // 64
#define WS_A3    36032      // 128
#define WS_C3    36160      // 128 -> 36288
#define WS_T1T   36288      // 131072  t1t[i*64+o]
#define WS_IS1T  167360     // 131072
#define WS_WW1T  298432     // -> 429504
#define WS_T2T   429504     // 4096
#define WS_IS2T  433600
#define WS_WW2T  437696
#define WS_T3T   441792
#define WS_IS3T  445888
#define WS_WW3T  449984     // -> 454080
#define WS_H2H   454080     // 1024*256*64 f16 = 8388608 floats
#define WS_H2L   8842688    // -> 17231296
#define WS_FEAT  17231296   // 1024*2048 floats -> end 19328448 (~77.3 MB, same as prev rounds)

typedef _Float16 f16x8 __attribute__((ext_vector_type(8)));
typedef float    f32x4 __attribute__((ext_vector_type(4)));

struct InPtrs { const float* p[34]; };

__device__ __forceinline__ float gelu_exact(float v) {
    return 0.5f * v * (1.0f + erff(v * 0.70710678118654752f));
}

// ---------------- prep: pack/transpose/split params ----------------
__global__ __launch_bounds__(256) void prep_kernel(InPtrs in, float* __restrict__ ws) {
    int idx = blockIdx.x * 256 + threadIdx.x;
    if (idx >= 453856) return;
    if (idx < 10240) {                       // w2 split hi/lo fp16 [co][tap*32+ci], stride 160
        int co = idx / 160; int kk = idx - co * 160;
        int tap = kk >> 5, ci = kk & 31;
        float val = in.p[7][co * 160 + ci * 5 + tap];
        _Float16 hi = (_Float16)val;
        ((_Float16*)(ws + WS_W2H))[co * 160 + kk] = hi;
        ((_Float16*)(ws + WS_W2L))[co * 160 + kk] = (_Float16)(val - (float)hi);
    } else if (idx < 35840) {                // w3 split hi/lo fp16 [co][tap*64+ci], stride 200
        int n = idx - 10240;
        int co = n / 200; int k = n - co * 200;
        float val = 0.0f;
        if (k < 192) { int ci = k & 63; int tap = k >> 6; val = in.p[13][co * 192 + ci * 3 + tap]; }
        _Float16 hi = (_Float16)val;
        ((_Float16*)(ws + WS_W3H))[co * 200 + k] = hi;
        ((_Float16*)(ws + WS_W3L))[co * 200 + k] = (_Float16)(val - (float)hi);
    } else if (idx < 36064) {                // BN folds
        int n = idx - 35840;
        int ch, offA, offC; const float *cb, *g, *bb, *m, *v;
        if (n < 32)      { ch = n;      cb = in.p[2];  g = in.p[3];  bb = in.p[4];  m = in.p[5];  v = in.p[6];  offA = WS_A1; offC = WS_C1; }
        else if (n < 96) { ch = n - 32; cb = in.p[8];  g = in.p[9];  bb = in.p[10]; m = in.p[11]; v = in.p[12]; offA = WS_A2; offC = WS_C2; }
        else             { ch = n - 96; cb = in.p[14]; g = in.p[15]; bb = in.p[16]; m = in.p[17]; v = in.p[18]; offA = WS_A3; offC = WS_C3; }
        float A = g[ch] * rsqrtf(v[ch] + 1e-5f);
        ws[offA + ch] = A;
        ws[offC + ch] = (cb[ch] - m[ch]) * A + bb[ch];
    } else if (idx < 429280) {               // wl1 transposes (t, 1/(s+1e-8), w)
        int n = idx - 36064;
        int arr = n / 131072; int m = n - arr * 131072;
        int o = m >> 11; int i = m & 2047;
        float val = in.p[19 + arr][o * 2048 + i];
        if (arr == 1) val = 1.0f / (val + 1e-8f);
        int base = (arr == 0) ? WS_T1T : (arr == 1) ? WS_IS1T : WS_WW1T;
        ws[base + i * 64 + o] = val;
    } else {                                 // wl2/wl3 transposes
        int n = idx - 429280;
        int layer = n / 12288; int m = n - layer * 12288;
        int arr = m / 4096; int mm = m - arr * 4096;
        int o = mm >> 6; int i = mm & 63;
        float val = in.p[(layer == 0 ? 24 : 29) + arr][o * 64 + i];
        if (arr == 1) val = 1.0f / (val + 1e-8f);
        int base;
        if (layer == 0) base = (arr == 0) ? WS_T2T : (arr == 1) ? WS_IS2T : WS_WW2T;
        else            base = (arr == 0) ? WS_T3T : (arr == 1) ? WS_IS3T : WS_WW3T;
        ws[base + i * 64 + o] = val;
    }
}

// ---------------- K12M: conv1+bn+gelu+pool (VALU) -> conv2 as split-fp16 MFMA -> bn+gelu+pool ----------------
// grid: 1024 b * 2 halves; block 256 = 4 waves. Per block: M=256 pre-pool conv2 pos, N=64, K=160.
// h1 tile in LDS split hi/lo fp16, stride 40 halves (m*20 dwords mod 32 -> 2-way = free).
__global__ __launch_bounds__(256) void k12m_kernel(const float* __restrict__ x,
                                                   const float* __restrict__ w1,
                                                   const float* __restrict__ ws,
                                                   _Float16* __restrict__ h2h,
                                                   _Float16* __restrict__ h2l) {
    __shared__ float xs[528];
    __shared__ float w1s[224];
    __shared__ float a1s[32], c1s[32], a2s[64], c2s[64];
    __shared__ __align__(16) _Float16 h1h[260 * 40];
    __shared__ __align__(16) _Float16 h1l[260 * 40];

    int t = threadIdx.x;
    int b = blockIdx.x >> 1, q = blockIdx.x & 1;
    int xoff = 512 * q - 7;

    for (int j = t; j < 526; j += 256) {
        int gx = xoff + j;
        xs[j] = (gx >= 0 && gx < 1024) ? x[b * 1024 + gx] : 0.0f;
    }
    if (t < 224) w1s[t] = w1[t];
    if (t < 32) { a1s[t] = ws[WS_A1 + t]; c1s[t] = ws[WS_C1 + t]; }
    if (t < 64) { a2s[t] = ws[WS_A2 + t]; c2s[t] = ws[WS_C2 + t]; }
    __syncthreads();

    // stage 1: conv1 + bn + gelu + maxpool2 -> h1 rows [256q-2, 256q+258)
    for (int item = t; item < 260 * 32; item += 256) {
        int r = item >> 5, ci = item & 31;
        int hp = 256 * q - 2 + r;
        float val = 0.0f;
        if (hp >= 0 && hp < 512) {
            float d0 = 0.0f, d1 = 0.0f;
            #pragma unroll
            for (int k = 0; k < 7; ++k) {
                float w = w1s[ci * 7 + k];
                d0 += w * xs[2 * r + k];
                d1 += w * xs[2 * r + k + 1];
            }
            float A = a1s[ci], C = c1s[ci];
            val = fmaxf(gelu_exact(d0 * A + C), gelu_exact(d1 * A + C));
        }
        _Float16 hi = (_Float16)val;
        h1h[r * 40 + ci] = hi;
        h1l[r * 40 + ci] = (_Float16)(val - (float)hi);
    }
    __syncthreads();

    // stage 2: conv2 GEMM. A[rowl][tap*32+ci] = h1[(rowl+tap)*40 + ci] (LDS),
    // B[co][kk] = w2{h,l}[co*160+kk] (global, L2-resident). 5 K-steps x 3 MFMAs.
    int w = t >> 6, lane = t & 63;
    int m = lane & 15, quad = lane >> 4;
    const _Float16* w2h = (const _Float16*)(ws + WS_W2H);
    const _Float16* w2l = (const _Float16*)(ws + WS_W2L);

    f32x4 acc[4][4] = {};
    #pragma unroll
    for (int s = 0; s < 5; ++s) {
        f16x8 ah[4], al[4], bh[4], bl[4];
        #pragma unroll
        for (int tr = 0; tr < 4; ++tr) {
            int rloc = 64 * w + 16 * tr + m + s;
            ah[tr] = *(const f16x8*)(&h1h[rloc * 40 + quad * 8]);
            al[tr] = *(const f16x8*)(&h1l[rloc * 40 + quad * 8]);
        }
        #pragma unroll
        for (int tc = 0; tc < 4; ++tc) {
            int off = (16 * tc + m) * 160 + 32 * s + quad * 8;
            bh[tc] = *(const f16x8*)(w2h + off);
            bl[tc] = *(const f16x8*)(w2l + off);
        }
        #pragma unroll
        for (int tr = 0; tr < 4; ++tr)
            #pragma unroll
            for (int tc = 0; tc < 4; ++tc) {
                acc[tr][tc] = __builtin_amdgcn_mfma_f32_16x16x32_f16(ah[tr], bh[tc], acc[tr][tc], 0, 0, 0);
                acc[tr][tc] = __builtin_amdgcn_mfma_f32_16x16x32_f16(al[tr], bh[tc], acc[tr][tc], 0, 0, 0);
                acc[tr][tc] = __builtin_amdgcn_mfma_f32_16x16x32_f16(ah[tr], bl[tc], acc[tr][tc], 0, 0, 0);
            }
    }

    // epilogue: bn + gelu + maxpool2 (pool pairs are adjacent acc regs -> in-lane), split-fp16 store.
    // C/D: col=lane&15 -> co=16tc+m; row=quad*4+reg -> rowl=64w+16tr+quad*4+reg.
    #pragma unroll
    for (int tc = 0; tc < 4; ++tc) {
        int co = 16 * tc + m;
        float A2 = a2s[co], C2 = c2s[co];
        #pragma unroll
        for (int tr = 0; tr < 4; ++tr) {
            float g0 = gelu_exact(acc[tr][tc][0] * A2 + C2);
            float g1 = gelu_exact(acc[tr][tc][1] * A2 + C2);
            float g2 = gelu_exact(acc[tr][tc][2] * A2 + C2);
            float g3 = gelu_exact(acc[tr][tc][3] * A2 + C2);
            float p0 = fmaxf(g0, g1), p1 = fmaxf(g2, g3);
            int rowl0 = 64 * w + 16 * tr + quad * 4;
            int lp = 128 * q + (rowl0 >> 1);
            size_t i0 = ((size_t)b * 256 + lp) * 64 + co;
            _Float16 h0 = (_Float16)p0, h1v = (_Float16)p1;
            h2h[i0] = h0;       h2l[i0] = (_Float16)(p0 - (float)h0);
            h2h[i0 + 64] = h1v; h2l[i0 + 64] = (_Float16)(p1 - (float)h1v);
        }
    }
}

// ---------------- K3M: conv3 as split-fp16 MFMA GEMM + bn + gelu + avgpool16 ----------------
// grid: 1024 b * 2 row-halves (128 l); block 256 = 4 waves (2x2); wave = 64 rows x 64 cols.
// A tile stride 88 halves = 44 dwords (m*12 mod 32 -> 8 banks, 2-way = free).
__global__ __launch_bounds__(256) void k3m_kernel(const _Float16* __restrict__ h2h,
                                                  const _Float16* __restrict__ h2l,
                                                  const _Float16* __restrict__ w3h,
                                                  const _Float16* __restrict__ w3l,
                                                  const float* __restrict__ ws,
                                                  float* __restrict__ feat) {
    __shared__ __align__(16) _Float16 Ah[130 * 88];
    __shared__ __align__(16) _Float16 Al[130 * 88];

    int t = threadIdx.x;
    int b = blockIdx.x >> 1, q = blockIdx.x & 1;
    int l0 = q * 128;

    for (int item = t; item < 130 * 8; item += 256) {
        int r = item >> 3, seg = item & 7;
        int l = l0 - 1 + r;
        uint4 vh = make_uint4(0u, 0u, 0u, 0u), vl = vh;
        if (l >= 0 && l < 256) {
            size_t base = ((size_t)b * 256 + l) * 64;
            vh = *((const uint4*)(h2h + base) + seg);
            vl = *((const uint4*)(h2l + base) + seg);
        }
        *(uint4*)(&Ah[r * 88 + seg * 8]) = vh;
        *(uint4*)(&Al[r * 88 + seg * 8]) = vl;
    }
    __syncthreads();

    int w = t >> 6, lane = t & 63;
    int wr = w >> 1, wc = w & 1;
    int m = lane & 15, quad = lane >> 4;

    f32x4 acc[4][4] = {};
    size_t boff = (size_t)(wc * 64 + m) * 200 + quad * 8;

    #pragma unroll
    for (int s = 0; s < 6; ++s) {
        int kbase = s * 32;
        int k = kbase + quad * 8;
        int koff = k >> 6, ci = k & 63;
        f16x8 ah[4], al[4], bh[4], bl[4];
        #pragma unroll
        for (int tr = 0; tr < 4; ++tr) {
            int row = 64 * wr + 16 * tr + m;
            ah[tr] = *(const f16x8*)(&Ah[(row + koff) * 88 + ci]);
            al[tr] = *(const f16x8*)(&Al[(row + koff) * 88 + ci]);
        }
        #pragma unroll
        for (int tc = 0; tc < 4; ++tc) {
            bh[tc] = *(const f16x8*)(w3h + boff + 16 * tc * 200 + kbase);
            bl[tc] = *(const f16x8*)(w3l + boff + 16 * tc * 200 + kbase);
        }
        #pragma unroll
        for (int tr = 0; tr < 4; ++tr)
            #pragma unroll
            for (int tc = 0; tc < 4; ++tc) {
                acc[tr][tc] = __builtin_amdgcn_mfma_f32_16x16x32_f16(ah[tr], bh[tc], acc[tr][tc], 0, 0, 0);
                acc[tr][tc] = __builtin_amdgcn_mfma_f32_16x16x32_f16(al[tr], bh[tc], acc[tr][tc], 0, 0, 0);
                acc[tr][tc] = __builtin_amdgcn_mfma_f32_16x16x32_f16(ah[tr], bl[tc], acc[tr][tc], 0, 0, 0);
            }
    }

    #pragma unroll
    for (int tc = 0; tc < 4; ++tc) {
        int co = 64 * wc + 16 * tc + m;
        float A3 = ws[WS_A3 + co], C3 = ws[WS_C3 + co];
        #pragma unroll
        for (int tr = 0; tr < 4; ++tr) {
            float s = 0.0f;
            #pragma unroll
            for (int r = 0; r < 4; ++r)
                s += gelu_exact(acc[tr][tc][r] * A3 + C3);
            s += __shfl_xor(s, 16, 64);
            s += __shfl_xor(s, 32, 64);
            if (quad == 0) {
                int bin = (l0 >> 4) + 4 * wr + tr;
                feat[(size_t)b * 2048 + co * 16 + bin] = s * 0.0625f;
            }
        }
    }
}

// ---------------- K4: wavelet-KAN head, fully fused ----------------
__device__ __forceinline__ float wave_sum(float v) {
    #pragma unroll
    for (int off = 32; off > 0; off >>= 1) v += __shfl_xor(v, off, 64);
    return v;
}
__device__ __forceinline__ float silu_f(float v) {
    return v / (1.0f + __expf(-v));
}

__global__ __launch_bounds__(256) void k4_kernel(const float* __restrict__ ws,
        const float* __restrict__ ln1g, const float* __restrict__ ln1b,
        const float* __restrict__ ln2g, const float* __restrict__ ln2b,
        const float* __restrict__ ln3g, const float* __restrict__ ln3b,
        float* __restrict__ out) {
    __shared__ __align__(16) float fs[4 * 2048];
    __shared__ float red[4 * 64 * 4];

    int t = threadIdx.x;
    int b0 = blockIdx.x * 4;
    const float* feat = ws + WS_FEAT;
    {
        const float4* src = (const float4*)(feat + (size_t)b0 * 2048);
        float4* dst = (float4*)fs;
        for (int i = t; i < 2048; i += 256) dst[i] = src[i];
    }
    __syncthreads();

    int o = t & 63, grp = t >> 6;
    const float* t1t  = ws + WS_T1T;
    const float* is1t = ws + WS_IS1T;
    const float* w1t  = ws + WS_WW1T;
    float acc0 = 0.0f, acc1 = 0.0f, acc2 = 0.0f, acc3 = 0.0f;
    int i0 = grp * 512;
    for (int i = i0; i < i0 + 512; ++i) {
        float tv = t1t[i * 64 + o], sv = is1t[i * 64 + o], wv = w1t[i * 64 + o];
        float z, z2;
        z = (fs[i] - tv) * sv;        z2 = z * z; acc0 += (1.0f - z2) * __expf(-0.5f * z2) * wv;
        z = (fs[2048 + i] - tv) * sv; z2 = z * z; acc1 += (1.0f - z2) * __expf(-0.5f * z2) * wv;
        z = (fs[4096 + i] - tv) * sv; z2 = z * z; acc2 += (1.0f - z2) * __expf(-0.5f * z2) * wv;
        z = (fs[6144 + i] - tv) * sv; z2 = z * z; acc3 += (1.0f - z2) * __expf(-0.5f * z2) * wv;
    }
    red[(0 * 64 + o) * 4 + grp] = acc0;
    red[(1 * 64 + o) * 4 + grp] = acc1;
    red[(2 * 64 + o) * 4 + grp] = acc2;
    red[(3 * 64 + o) * 4 + grp] = acc3;
    __syncthreads();

    int w = t >> 6;
    float y = red[(w * 64 + o) * 4 + 0] + red[(w * 64 + o) * 4 + 1]
            + red[(w * 64 + o) * 4 + 2] + red[(w * 64 + o) * 4 + 3];

    y = silu_f(y);
    float m = wave_sum(y) * 0.015625f;
    float d = y - m;
    float var = wave_sum(d * d) * 0.015625f;
    float yn = d * rsqrtf(var + 1e-5f) * ln1g[o] + ln1b[o];

    {
        const float* t2t  = ws + WS_T2T;
        const float* is2t = ws + WS_IS2T;
        const float* w2t  = ws + WS_WW2T;
        float a = 0.0f;
        for (int i = 0; i < 64; ++i) {
            float xi = __shfl(yn, i, 64);
            float tv = t2t[i * 64 + o], sv = is2t[i * 64 + o], wv = w2t[i * 64 + o];
            float z = (xi - tv) * sv, z2 = z * z;
            a += (1.0f - z2) * __expf(-0.5f * z2) * wv;
        }
        float y2 = silu_f(a);
        float m2 = wave_sum(y2) * 0.015625f;
        float d2 = y2 - m2;
        float v2 = wave_sum(d2 * d2) * 0.015625f;
        yn = d2 * rsqrtf(v2 + 1e-5f) * ln2g[o] + ln2b[o];
    }
    {
        const float* t3t  = ws + WS_T3T;
        const float* is3t = ws + WS_IS3T;
        const float* w3t  = ws + WS_WW3T;
        float a = 0.0f;
        for (int i = 0; i < 64; ++i) {
            float xi = __shfl(yn, i, 64);
            float tv = t3t[i * 64 + o], sv = is3t[i * 64 + o], wv = w3t[i * 64 + o];
            float z = (xi - tv) * sv, z2 = z * z;
            a += (1.0f - z2) * __expf(-0.5f * z2) * wv;
        }
        float y3 = silu_f(a);
        float m3 = wave_sum(y3) * 0.015625f;
        float d3 = y3 - m3;
        float v3 = wave_sum(d3 * d3) * 0.015625f;
        yn = d3 * rsqrtf(v3 + 1e-5f) * ln3g[o] + ln3b[o];
    }
    out[((size_t)b0 + w) * 64 + o] = yn;
}

// ---------------- launch ----------------
extern "C" void kernel_launch(void* const* d_in, const int* in_sizes, int n_in,
                              void* d_out, int out_size, void* d_ws, size_t ws_size,
                              hipStream_t stream) {
    float* ws = (float*)d_ws;
    InPtrs ip;
    for (int i = 0; i < 34; ++i) ip.p[i] = (const float*)d_in[i];

    prep_kernel<<<1774, 256, 0, stream>>>(ip, ws);
    k12m_kernel<<<2048, 256, 0, stream>>>((const float*)d_in[0], (const float*)d_in[1],
                                          ws,
                                          (_Float16*)(ws + WS_H2H),
                                          (_Float16*)(ws + WS_H2L));
    k3m_kernel<<<2048, 256, 0, stream>>>((const _Float16*)(ws + WS_H2H),
                                         (const _Float16*)(ws + WS_H2L),
                                         (const _Float16*)(ws + WS_W3H),
                                         (const _Float16*)(ws + WS_W3L),
                                         ws, ws + WS_FEAT);
    k4_kernel<<<256, 256, 0, stream>>>(ws,
        (const float*)d_in[22], (const float*)d_in[23],
        (const float*)d_in[27], (const float*)d_in[28],
        (const float*)d_in[32], (const float*)d_in[33],
        (float*)d_out);
}

// Round 5
// 299.547 us; speedup vs baseline: 2.7933x; 1.3617x over previous
//
#include <hip/hip_runtime.h>
#include <hip/hip_bf16.h>
#include <math.h>

// ---------------- workspace layout (float offsets) ----------------
#define WS_W2H   0          // 64*160 f16 = 5120 floats   w2h[co*160 + (tap*32+ci)]
#define WS_W2L   5120       // residual plane
#define WS_W3H   10240      // 128*200 f16 = 12800 floats w3h[co*200 + (tap*64+ci)]
#define WS_W3L   23040      // -> 35840
#define WS_A1    35840      // 32
#define WS_C1    35872      // 32
#define WS_A2    35904      // 64
#define WS_C2    35968      // 64
#define WS_A3    36032      // 128
#define WS_C3    36160      // 128 -> 36288
#define WS_T1T   36288      // 131072  t1t[i*64+o]
#define WS_IS1T  167360     // 131072
#define WS_WW1T  298432     // -> 429504
#define WS_T2T   429504     // 4096
#define WS_IS2T  433600
#define WS_WW2T  437696
#define WS_T3T   441792
#define WS_IS3T  445888
#define WS_WW3T  449984     // -> 454080
#define WS_H2H   454080     // 1024*256*64 f16 = 8388608 floats
#define WS_H2L   8842688    // -> 17231296
#define WS_FEAT  17231296   // 1024*2048 floats -> end 19328448

typedef _Float16 f16x8 __attribute__((ext_vector_type(8)));
typedef float    f32x4 __attribute__((ext_vector_type(4)));

struct InPtrs { const float* p[34]; };

// Branchless A&S 7.1.26 erf-based gelu: |erf err| <= 1.5e-7, ~16 VALU ops, no branches.
__device__ __forceinline__ float gelu_fast(float x) {
    float z  = 0.70710678118654752f * x;
    float az = fabsf(z);
    float t  = __builtin_amdgcn_rcpf(fmaf(0.3275911f, az, 1.0f));
    float p  = fmaf(1.061405429f, t, -1.453152027f);
    p = fmaf(p, t, 1.421413741f);
    p = fmaf(p, t, -0.284496736f);
    p = fmaf(p, t, 0.254829592f);
    p = p * t;
    float e  = __expf(-z * z);
    float erf_abs = fmaf(-p, e, 1.0f);
    float erfv = copysignf(erf_abs, z);
    return 0.5f * x * (1.0f + erfv);
}

// ---------------- prep: pack/transpose/split params ----------------
__global__ __launch_bounds__(256) void prep_kernel(InPtrs in, float* __restrict__ ws) {
    int idx = blockIdx.x * 256 + threadIdx.x;
    if (idx >= 453856) return;
    if (idx < 10240) {                       // w2 split hi/lo fp16 [co][tap*32+ci], stride 160
        int co = idx / 160; int kk = idx - co * 160;
        int tap = kk >> 5, ci = kk & 31;
        float val = in.p[7][co * 160 + ci * 5 + tap];
        _Float16 hi = (_Float16)val;
        ((_Float16*)(ws + WS_W2H))[co * 160 + kk] = hi;
        ((_Float16*)(ws + WS_W2L))[co * 160 + kk] = (_Float16)(val - (float)hi);
    } else if (idx < 35840) {                // w3 split hi/lo fp16 [co][tap*64+ci], stride 200
        int n = idx - 10240;
        int co = n / 200; int k = n - co * 200;
        float val = 0.0f;
        if (k < 192) { int ci = k & 63; int tap = k >> 6; val = in.p[13][co * 192 + ci * 3 + tap]; }
        _Float16 hi = (_Float16)val;
        ((_Float16*)(ws + WS_W3H))[co * 200 + k] = hi;
        ((_Float16*)(ws + WS_W3L))[co * 200 + k] = (_Float16)(val - (float)hi);
    } else if (idx < 36064) {                // BN folds
        int n = idx - 35840;
        int ch, offA, offC; const float *cb, *g, *bb, *m, *v;
        if (n < 32)      { ch = n;      cb = in.p[2];  g = in.p[3];  bb = in.p[4];  m = in.p[5];  v = in.p[6];  offA = WS_A1; offC = WS_C1; }
        else if (n < 96) { ch = n - 32; cb = in.p[8];  g = in.p[9];  bb = in.p[10]; m = in.p[11]; v = in.p[12]; offA = WS_A2; offC = WS_C2; }
        else             { ch = n - 96; cb = in.p[14]; g = in.p[15]; bb = in.p[16]; m = in.p[17]; v = in.p[18]; offA = WS_A3; offC = WS_C3; }
        float A = g[ch] * rsqrtf(v[ch] + 1e-5f);
        ws[offA + ch] = A;
        ws[offC + ch] = (cb[ch] - m[ch]) * A + bb[ch];
    } else if (idx < 429280) {               // wl1 transposes (t, 1/(s+1e-8), w)
        int n = idx - 36064;
        int arr = n / 131072; int m = n - arr * 131072;
        int o = m >> 11; int i = m & 2047;
        float val = in.p[19 + arr][o * 2048 + i];
        if (arr == 1) val = 1.0f / (val + 1e-8f);
        int base = (arr == 0) ? WS_T1T : (arr == 1) ? WS_IS1T : WS_WW1T;
        ws[base + i * 64 + o] = val;
    } else {                                 // wl2/wl3 transposes
        int n = idx - 429280;
        int layer = n / 12288; int m = n - layer * 12288;
        int arr = m / 4096; int mm = m - arr * 4096;
        int o = mm >> 6; int i = mm & 63;
        float val = in.p[(layer == 0 ? 24 : 29) + arr][o * 64 + i];
        if (arr == 1) val = 1.0f / (val + 1e-8f);
        int base;
        if (layer == 0) base = (arr == 0) ? WS_T2T : (arr == 1) ? WS_IS2T : WS_WW2T;
        else            base = (arr == 0) ? WS_T3T : (arr == 1) ? WS_IS3T : WS_WW3T;
        ws[base + i * 64 + o] = val;
    }
}

// ---------------- K12M: conv1+bn+gelu+pool (VALU) -> conv2 split-fp16 MFMA -> bn+gelu+pool ----------------
__global__ __launch_bounds__(256) void k12m_kernel(const float* __restrict__ x,
                                                   const float* __restrict__ w1,
                                                   const float* __restrict__ ws,
                                                   _Float16* __restrict__ h2h,
                                                   _Float16* __restrict__ h2l) {
    __shared__ float xs[528];
    __shared__ float w1s[224];
    __shared__ float a1s[32], c1s[32], a2s[64], c2s[64];
    __shared__ __align__(16) _Float16 h1h[260 * 40];
    __shared__ __align__(16) _Float16 h1l[260 * 40];

    int t = threadIdx.x;
    int b = blockIdx.x >> 1, q = blockIdx.x & 1;
    int xoff = 512 * q - 7;

    for (int j = t; j < 526; j += 256) {
        int gx = xoff + j;
        xs[j] = (gx >= 0 && gx < 1024) ? x[b * 1024 + gx] : 0.0f;
    }
    if (t < 224) w1s[t] = w1[t];
    if (t < 32) { a1s[t] = ws[WS_A1 + t]; c1s[t] = ws[WS_C1 + t]; }
    if (t < 64) { a2s[t] = ws[WS_A2 + t]; c2s[t] = ws[WS_C2 + t]; }
    __syncthreads();

    for (int item = t; item < 260 * 32; item += 256) {
        int r = item >> 5, ci = item & 31;
        int hp = 256 * q - 2 + r;
        float val = 0.0f;
        if (hp >= 0 && hp < 512) {
            float d0 = 0.0f, d1 = 0.0f;
            #pragma unroll
            for (int k = 0; k < 7; ++k) {
                float w = w1s[ci * 7 + k];
                d0 += w * xs[2 * r + k];
                d1 += w * xs[2 * r + k + 1];
            }
            float A = a1s[ci], C = c1s[ci];
            val = fmaxf(gelu_fast(d0 * A + C), gelu_fast(d1 * A + C));
        }
        _Float16 hi = (_Float16)val;
        h1h[r * 40 + ci] = hi;
        h1l[r * 40 + ci] = (_Float16)(val - (float)hi);
    }
    __syncthreads();

    int w = t >> 6, lane = t & 63;
    int m = lane & 15, quad = lane >> 4;
    const _Float16* w2h = (const _Float16*)(ws + WS_W2H);
    const _Float16* w2l = (const _Float16*)(ws + WS_W2L);

    f32x4 acc[4][4] = {};
    #pragma unroll
    for (int s = 0; s < 5; ++s) {
        f16x8 ah[4], al[4], bh[4], bl[4];
        #pragma unroll
        for (int tr = 0; tr < 4; ++tr) {
            int rloc = 64 * w + 16 * tr + m + s;
            ah[tr] = *(const f16x8*)(&h1h[rloc * 40 + quad * 8]);
            al[tr] = *(const f16x8*)(&h1l[rloc * 40 + quad * 8]);
        }
        #pragma unroll
        for (int tc = 0; tc < 4; ++tc) {
            int off = (16 * tc + m) * 160 + 32 * s + quad * 8;
            bh[tc] = *(const f16x8*)(w2h + off);
            bl[tc] = *(const f16x8*)(w2l + off);
        }
        #pragma unroll
        for (int tr = 0; tr < 4; ++tr)
            #pragma unroll
            for (int tc = 0; tc < 4; ++tc) {
                acc[tr][tc] = __builtin_amdgcn_mfma_f32_16x16x32_f16(ah[tr], bh[tc], acc[tr][tc], 0, 0, 0);
                acc[tr][tc] = __builtin_amdgcn_mfma_f32_16x16x32_f16(al[tr], bh[tc], acc[tr][tc], 0, 0, 0);
                acc[tr][tc] = __builtin_amdgcn_mfma_f32_16x16x32_f16(ah[tr], bl[tc], acc[tr][tc], 0, 0, 0);
            }
    }

    #pragma unroll
    for (int tc = 0; tc < 4; ++tc) {
        int co = 16 * tc + m;
        float A2 = a2s[co], C2 = c2s[co];
        #pragma unroll
        for (int tr = 0; tr < 4; ++tr) {
            float g0 = gelu_fast(acc[tr][tc][0] * A2 + C2);
            float g1 = gelu_fast(acc[tr][tc][1] * A2 + C2);
            float g2 = gelu_fast(acc[tr][tc][2] * A2 + C2);
            float g3 = gelu_fast(acc[tr][tc][3] * A2 + C2);
            float p0 = fmaxf(g0, g1), p1 = fmaxf(g2, g3);
            int rowl0 = 64 * w + 16 * tr + quad * 4;
            int lp = 128 * q + (rowl0 >> 1);
            size_t i0 = ((size_t)b * 256 + lp) * 64 + co;
            _Float16 h0 = (_Float16)p0, h1v = (_Float16)p1;
            h2h[i0] = h0;       h2l[i0] = (_Float16)(p0 - (float)h0);
            h2h[i0 + 64] = h1v; h2l[i0 + 64] = (_Float16)(p1 - (float)h1v);
        }
    }
}

// ---------------- K3M: conv3 split-fp16 MFMA GEMM + bn + gelu + avgpool16 ----------------
__global__ __launch_bounds__(256) void k3m_kernel(const _Float16* __restrict__ h2h,
                                                  const _Float16* __restrict__ h2l,
                                                  const _Float16* __restrict__ w3h,
                                                  const _Float16* __restrict__ w3l,
                                                  const float* __restrict__ ws,
                                                  float* __restrict__ feat) {
    __shared__ __align__(16) _Float16 Ah[130 * 88];
    __shared__ __align__(16) _Float16 Al[130 * 88];

    int t = threadIdx.x;
    int b = blockIdx.x >> 1, q = blockIdx.x & 1;
    int l0 = q * 128;

    for (int item = t; item < 130 * 8; item += 256) {
        int r = item >> 3, seg = item & 7;
        int l = l0 - 1 + r;
        uint4 vh = make_uint4(0u, 0u, 0u, 0u), vl = vh;
        if (l >= 0 && l < 256) {
            size_t base = ((size_t)b * 256 + l) * 64;
            vh = *((const uint4*)(h2h + base) + seg);
            vl = *((const uint4*)(h2l + base) + seg);
        }
        *(uint4*)(&Ah[r * 88 + seg * 8]) = vh;
        *(uint4*)(&Al[r * 88 + seg * 8]) = vl;
    }
    __syncthreads();

    int w = t >> 6, lane = t & 63;
    int wr = w >> 1, wc = w & 1;
    int m = lane & 15, quad = lane >> 4;

    f32x4 acc[4][4] = {};
    size_t boff = (size_t)(wc * 64 + m) * 200 + quad * 8;

    #pragma unroll
    for (int s = 0; s < 6; ++s) {
        int kbase = s * 32;
        int k = kbase + quad * 8;
        int koff = k >> 6, ci = k & 63;
        f16x8 ah[4], al[4], bh[4], bl[4];
        #pragma unroll
        for (int tr = 0; tr < 4; ++tr) {
            int row = 64 * wr + 16 * tr + m;
            ah[tr] = *(const f16x8*)(&Ah[(row + koff) * 88 + ci]);
            al[tr] = *(const f16x8*)(&Al[(row + koff) * 88 + ci]);
        }
        #pragma unroll
        for (int tc = 0; tc < 4; ++tc) {
            bh[tc] = *(const f16x8*)(w3h + boff + 16 * tc * 200 + kbase);
            bl[tc] = *(const f16x8*)(w3l + boff + 16 * tc * 200 + kbase);
        }
        #pragma unroll
        for (int tr = 0; tr < 4; ++tr)
            #pragma unroll
            for (int tc = 0; tc < 4; ++tc) {
                acc[tr][tc] = __builtin_amdgcn_mfma_f32_16x16x32_f16(ah[tr], bh[tc], acc[tr][tc], 0, 0, 0);
                acc[tr][tc] = __builtin_amdgcn_mfma_f32_16x16x32_f16(al[tr], bh[tc], acc[tr][tc], 0, 0, 0);
                acc[tr][tc] = __builtin_amdgcn_mfma_f32_16x16x32_f16(ah[tr], bl[tc], acc[tr][tc], 0, 0, 0);
            }
    }

    #pragma unroll
    for (int tc = 0; tc < 4; ++tc) {
        int co = 64 * wc + 16 * tc + m;
        float A3 = ws[WS_A3 + co], C3 = ws[WS_C3 + co];
        #pragma unroll
        for (int tr = 0; tr < 4; ++tr) {
            float s = 0.0f;
            #pragma unroll
            for (int r = 0; r < 4; ++r)
                s += gelu_fast(acc[tr][tc][r] * A3 + C3);
            s += __shfl_xor(s, 16, 64);
            s += __shfl_xor(s, 32, 64);
            if (quad == 0) {
                int bin = (l0 >> 4) + 4 * wr + tr;
                feat[(size_t)b * 2048 + co * 16 + bin] = s * 0.0625f;
            }
        }
    }
}

// ---------------- K4: wavelet-KAN head, fully fused ----------------
// grid 256 blocks x 1024 threads (16 waves = 4 waves/SIMD). 4 batch rows/block,
// wl1 i-dim split into 16 chunks of 128; red[chunk][row][lane] (lane-stride-1, conflict-free).
__device__ __forceinline__ float wave_sum(float v) {
    #pragma unroll
    for (int off = 32; off > 0; off >>= 1) v += __shfl_xor(v, off, 64);
    return v;
}
__device__ __forceinline__ float silu_f(float v) {
    return v / (1.0f + __expf(-v));
}

__global__ __launch_bounds__(1024) void k4_kernel(const float* __restrict__ ws,
        const float* __restrict__ ln1g, const float* __restrict__ ln1b,
        const float* __restrict__ ln2g, const float* __restrict__ ln2b,
        const float* __restrict__ ln3g, const float* __restrict__ ln3b,
        float* __restrict__ out) {
    __shared__ __align__(16) float fs[4 * 2048];
    __shared__ float red[16 * 256];

    int t = threadIdx.x;
    int b0 = blockIdx.x * 4;
    const float* feat = ws + WS_FEAT;
    {
        const float4* src = (const float4*)(feat + (size_t)b0 * 2048);
        float4* dst = (float4*)fs;
        for (int i = t; i < 2048; i += 1024) dst[i] = src[i];
    }
    __syncthreads();

    int o = t & 63, grp = t >> 6;   // grp == wave id, 0..15
    const float* t1t  = ws + WS_T1T;
    const float* is1t = ws + WS_IS1T;
    const float* w1t  = ws + WS_WW1T;
    float acc0 = 0.0f, acc1 = 0.0f, acc2 = 0.0f, acc3 = 0.0f;
    int i0 = grp * 128;
    for (int i = i0; i < i0 + 128; ++i) {
        float tv = t1t[i * 64 + o], sv = is1t[i * 64 + o], wv = w1t[i * 64 + o];
        float z, z2;
        z = (fs[i] - tv) * sv;        z2 = z * z; acc0 += (1.0f - z2) * __expf(-0.5f * z2) * wv;
        z = (fs[2048 + i] - tv) * sv; z2 = z * z; acc1 += (1.0f - z2) * __expf(-0.5f * z2) * wv;
        z = (fs[4096 + i] - tv) * sv; z2 = z * z; acc2 += (1.0f - z2) * __expf(-0.5f * z2) * wv;
        z = (fs[6144 + i] - tv) * sv; z2 = z * z; acc3 += (1.0f - z2) * __expf(-0.5f * z2) * wv;
    }
    red[grp * 256 + 0 * 64 + o] = acc0;
    red[grp * 256 + 1 * 64 + o] = acc1;
    red[grp * 256 + 2 * 64 + o] = acc2;
    red[grp * 256 + 3 * 64 + o] = acc3;
    __syncthreads();

    if (grp < 4) {
        int w = grp;  // wave -> batch row b0+w, lane -> o
        float y = 0.0f;
        #pragma unroll
        for (int j = 0; j < 16; ++j) y += red[j * 256 + w * 64 + o];

        y = silu_f(y);
        float m = wave_sum(y) * 0.015625f;
        float d = y - m;
        float var = wave_sum(d * d) * 0.015625f;
        float yn = d * rsqrtf(var + 1e-5f) * ln1g[o] + ln1b[o];

        {
            const float* t2t  = ws + WS_T2T;
            const float* is2t = ws + WS_IS2T;
            const float* w2t  = ws + WS_WW2T;
            float a = 0.0f;
            for (int i = 0; i < 64; ++i) {
                float xi = __shfl(yn, i, 64);
                float tv = t2t[i * 64 + o], sv = is2t[i * 64 + o], wv = w2t[i * 64 + o];
                float z = (xi - tv) * sv, z2 = z * z;
                a += (1.0f - z2) * __expf(-0.5f * z2) * wv;
            }
            float y2 = silu_f(a);
            float m2 = wave_sum(y2) * 0.015625f;
            float d2 = y2 - m2;
            float v2 = wave_sum(d2 * d2) * 0.015625f;
            yn = d2 * rsqrtf(v2 + 1e-5f) * ln2g[o] + ln2b[o];
        }
        {
            const float* t3t  = ws + WS_T3T;
            const float* is3t = ws + WS_IS3T;
            const float* w3t  = ws + WS_WW3T;
            float a = 0.0f;
            for (int i = 0; i < 64; ++i) {
                float xi = __shfl(yn, i, 64);
                float tv = t3t[i * 64 + o], sv = is3t[i * 64 + o], wv = w3t[i * 64 + o];
                float z = (xi - tv) * sv, z2 = z * z;
                a += (1.0f - z2) * __expf(-0.5f * z2) * wv;
            }
            float y3 = silu_f(a);
            float m3 = wave_sum(y3) * 0.015625f;
            float d3 = y3 - m3;
            float v3 = wave_sum(d3 * d3) * 0.015625f;
            yn = d3 * rsqrtf(v3 + 1e-5f) * ln3g[o] + ln3b[o];
        }
        out[((size_t)b0 + w) * 64 + o] = yn;
    }
}

// ---------------- launch ----------------
extern "C" void kernel_launch(void* const* d_in, const int* in_sizes, int n_in,
                              void* d_out, int out_size, void* d_ws, size_t ws_size,
                              hipStream_t stream) {
    float* ws = (float*)d_ws;
    InPtrs ip;
    for (int i = 0; i < 34; ++i) ip.p[i] = (const float*)d_in[i];

    prep_kernel<<<1774, 256, 0, stream>>>(ip, ws);
    k12m_kernel<<<2048, 256, 0, stream>>>((const float*)d_in[0], (const float*)d_in[1],
                                          ws,
                                          (_Float16*)(ws + WS_H2H),
                                          (_Float16*)(ws + WS_H2L));
    k3m_kernel<<<2048, 256, 0, stream>>>((const _Float16*)(ws + WS_H2H),
                                         (const _Float16*)(ws + WS_H2L),
                                         (const _Float16*)(ws + WS_W3H),
                                         (const _Float16*)(ws + WS_W3L),
                                         ws, ws + WS_FEAT);
    k4_kernel<<<256, 1024, 0, stream>>>(ws,
        (const float*)d_in[22], (const float*)d_in[23],
        (const float*)d_in[27], (const float*)d_in[28],
        (const float*)d_in[32], (const float*)d_in[33],
        (float*)d_out);
}